// Round 7
// baseline (566.338 us; speedup 1.0000x reference)
//
#include <hip/hip_runtime.h>

#define N_NODES 65536
#define B_G     16
#define NPG_    4096
#define H_H     2
#define D_D     64
#define HD      128
#define E_E     524288
#define D_OUT   64

// ---------------- degree / CSR build ----------------

__global__ void deg_kernel(const int* __restrict__ col, int* __restrict__ degi) {
    int e = blockIdx.x * 256 + threadIdx.x;
    if (e < E_E) atomicAdd(&degi[col[e]], 1);
}

// block-local exclusive scan of degrees; also emits dinv = deg^-1/2 (fused).
__global__ void scan1(const int* __restrict__ degi, int* __restrict__ ptr,
                      int* __restrict__ bsums, float* __restrict__ dinv) {
    __shared__ int lds[256];
    int t = threadIdx.x;
    int i = blockIdx.x * 256 + t;
    int v = degi[i];
    dinv[i] = (v > 0) ? (1.0f / sqrtf((float)v)) : 0.0f;
    lds[t] = v;
    __syncthreads();
    for (int off = 1; off < 256; off <<= 1) {
        int tmp = (t >= off) ? lds[t - off] : 0;
        __syncthreads();
        lds[t] += tmp;
        __syncthreads();
    }
    ptr[i] = lds[t] - v;
    if (t == 255) bsums[blockIdx.x] = lds[255];
}

// adds prefix of bsums[0..bid-1] (computed in-block; absorbs old scan2).
__global__ void scan3(int* __restrict__ ptr, const int* __restrict__ bsums) {
    __shared__ int red[256];
    int t = threadIdx.x;
    red[t] = (t < (int)blockIdx.x) ? bsums[t] : 0;
    __syncthreads();
    for (int off = 128; off > 0; off >>= 1) {
        if (t < off) red[t] += red[t + off];
        __syncthreads();
    }
    int i = blockIdx.x * 256 + t;
    ptr[i] += red[0];
    if (i == 0) ptr[N_NODES] = E_E;
}

__global__ void scatter_kernel(const int* __restrict__ row, const int* __restrict__ col,
                               const int* __restrict__ ptr, int* __restrict__ cursor,
                               const float* __restrict__ dinv,
                               int2* __restrict__ ep) {
    int e = blockIdx.x * 256 + threadIdx.x;
    if (e < E_E) {
        int c = col[e], r = row[e];
        int p = ptr[c] + atomicAdd(&cursor[c], 1);
        ep[p] = make_int2(r, __float_as_int(dinv[c] * dinv[r]));
    }
}

// ---------------- q/k projection + fused L2-normalize ----------------
// Exact out_kernel structure (proven): W^T in LDS (stride 65, 2-way free),
// x rows read as wave-uniform global float4 broadcasts (L1-resident), 4-node
// register blocking -> 1 ds_read_b128 + 4 uniform VMEM per 16 FMA.
// grid 2048: bid&1 = q/k, 64 nodes/block. Wave = one head's 64 cols -> sumsq
// butterfly is wave-local.
__global__ __launch_bounds__(256) void proj_kernel(
    const float* __restrict__ x,
    const float* __restrict__ Wq, const float* __restrict__ bq,
    const float* __restrict__ Wk, const float* __restrict__ bk,
    float* __restrict__ qs, float* __restrict__ ks) {
    __shared__ float wt[128 * 65];
    __shared__ float bl[128];
    int t = threadIdx.x;
    int qk = blockIdx.x & 1;
    int nb = (blockIdx.x >> 1) * 64;
    const float* W = qk ? Wk : Wq;
    const float* bias = qk ? bk : bq;
    float* outp = qk ? ks : qs;

    for (int i = t; i < 8192; i += 256) {
        int k = i >> 7, c = i & 127;
        wt[c * 65 + k] = W[i];
    }
    if (t < 128) bl[t] = bias[t];
    __syncthreads();

    int col = t & 127;
    int seg = t >> 7;
    const float* wcol = wt + col * 65;
    float bcol = bl[col];
    for (int g = 0; g < 8; ++g) {
        int n0 = seg * 32 + g * 4;
        const float4* xr0 = (const float4*)(x + (size_t)(nb + n0 + 0) * 64);
        const float4* xr1 = (const float4*)(x + (size_t)(nb + n0 + 1) * 64);
        const float4* xr2 = (const float4*)(x + (size_t)(nb + n0 + 2) * 64);
        const float4* xr3 = (const float4*)(x + (size_t)(nb + n0 + 3) * 64);
        float a0 = 0.f, a1 = 0.f, a2 = 0.f, a3 = 0.f;
#pragma unroll 4
        for (int k4 = 0; k4 < 16; ++k4) {
            float4 w = *(const float4*)(wcol + k4 * 4);
            float4 v0 = xr0[k4], v1 = xr1[k4], v2 = xr2[k4], v3 = xr3[k4];
            a0 += w.x * v0.x + w.y * v0.y + w.z * v0.z + w.w * v0.w;
            a1 += w.x * v1.x + w.y * v1.y + w.z * v1.z + w.w * v1.w;
            a2 += w.x * v2.x + w.y * v2.y + w.z * v2.z + w.w * v2.w;
            a3 += w.x * v3.x + w.y * v3.y + w.z * v3.z + w.w * v3.w;
        }
        a0 += bcol; a1 += bcol; a2 += bcol; a3 += bcol;
        float s0 = a0 * a0, s1 = a1 * a1, s2 = a2 * a2, s3 = a3 * a3;
#pragma unroll
        for (int off = 32; off > 0; off >>= 1) {
            s0 += __shfl_xor(s0, off);
            s1 += __shfl_xor(s1, off);
            s2 += __shfl_xor(s2, off);
            s3 += __shfl_xor(s3, off);
        }
        outp[(size_t)(nb + n0 + 0) * 128 + col] = a0 * rsqrtf(s0);
        outp[(size_t)(nb + n0 + 1) * 128 + col] = a1 * rsqrtf(s1);
        outp[(size_t)(nb + n0 + 2) * 128 + col] = a2 * rsqrtf(s2);
        outp[(size_t)(nb + n0 + 3) * 128 + col] = a3 * rsqrtf(s3);
    }
}

// ---------------- kvs = K^T X per (b,h); plus ksum, xsum ----------------
// 1024 blocks: (bh, 32 chunks of 128 nodes) -> 4 blocks/CU.
__global__ __launch_bounds__(256) void kvs_kernel(
    const float* __restrict__ ks, const float* __restrict__ x,
    float* __restrict__ kvs, float* __restrict__ ksum, float* __restrict__ xsum) {
    int bid = blockIdx.x;
    int chunk = bid & 31;
    int bh = bid >> 5;
    int b = bh >> 1, h = bh & 1;
    int t = threadIdx.x;
    int mrow = t >> 4, dcol = t & 15;
    int m0 = mrow * 4, d0 = dcol * 4;
    __shared__ float kl[32 * 64];
    __shared__ float xl[32 * 64];
    float acc[4][4] = {{0}};
    float ksacc[4] = {0, 0, 0, 0};
    float xsacc[4] = {0, 0, 0, 0};
    int node0 = b * NPG_ + chunk * 128;
    for (int s = 0; s < 4; ++s) {
        int nb = node0 + s * 32;
        for (int i = t; i < 512; i += 256) {
            int l = i >> 4, q = i & 15;
            ((float4*)kl)[i] = *(const float4*)(ks + (size_t)(nb + l) * 128 + h * 64 + q * 4);
        }
        const float4* xg = (const float4*)(x + (size_t)nb * 64);
        for (int i = t; i < 512; i += 256) ((float4*)xl)[i] = xg[i];
        __syncthreads();
        for (int l = 0; l < 32; ++l) {
            float4 kv = *(float4*)(kl + l * 64 + m0);
            float4 xv = *(float4*)(xl + l * 64 + d0);
            float kk[4] = {kv.x, kv.y, kv.z, kv.w};
            float xx[4] = {xv.x, xv.y, xv.z, xv.w};
#pragma unroll
            for (int i = 0; i < 4; ++i)
#pragma unroll
                for (int j = 0; j < 4; ++j) acc[i][j] += kk[i] * xx[j];
            if (dcol == 0) {
#pragma unroll
                for (int i = 0; i < 4; ++i) ksacc[i] += kk[i];
            }
            if (mrow == 0) {
#pragma unroll
                for (int j = 0; j < 4; ++j) xsacc[j] += xx[j];
            }
        }
        __syncthreads();
    }
#pragma unroll
    for (int i = 0; i < 4; ++i)
#pragma unroll
        for (int j = 0; j < 4; ++j)
            atomicAdd(&kvs[(bh * 64 + m0 + i) * 64 + d0 + j], acc[i][j]);
    if (dcol == 0) {
#pragma unroll
        for (int i = 0; i < 4; ++i) atomicAdd(&ksum[bh * 64 + m0 + i], ksacc[i]);
    }
    if (mrow == 0 && h == 0) {
#pragma unroll
        for (int j = 0; j < 4; ++j) atomicAdd(&xsum[b * 64 + d0 + j], xsacc[j]);
    }
}

// ---------------- attention output: block = 128 nodes x 1 head ----------------
__global__ __launch_bounds__(256) void attn_kernel(
    const float* __restrict__ qs, const float* __restrict__ kvs,
    const float* __restrict__ ksum, const float* __restrict__ xsum,
    float* __restrict__ attn) {
    __shared__ float ql[128 * 64];
    int bid = blockIdx.x;
    int h = bid & 1;
    int nb = (bid >> 1) * 128;
    int b = nb >> 12;
    int bh = b * 2 + h;
    int t = threadIdx.x;
    int lane = t & 63;
    for (int i = t; i < 128 * 16; i += 256) {
        int r = i >> 4, q4 = i & 15;
        ((float4*)ql)[i] = *(const float4*)(qs + (size_t)(nb + r) * 128 + h * 64 + q4 * 4);
    }
    float kvreg[64];
    const float* kvp = kvs + bh * 4096 + lane;
#pragma unroll
    for (int m = 0; m < 64; ++m) kvreg[m] = kvp[m * 64];
    float ksreg = ksum[bh * 64 + lane];
    float xs_d = xsum[b * 64 + lane];
    __syncthreads();
    int nslot = t >> 6;
    for (int nn = 0; nn < 32; ++nn) {
        int node = nn * 4 + nslot;
        const float* qrow = ql + node * 64;
        float p = qrow[lane] * ksreg;
#pragma unroll
        for (int off = 32; off > 0; off >>= 1) p += __shfl_xor(p, off);
        float den = p + 16.0f;
        float acc = 0.f;
#pragma unroll
        for (int m4 = 0; m4 < 16; ++m4) {
            float4 qv = *(const float4*)(qrow + m4 * 4);
            acc += qv.x * kvreg[4 * m4] + qv.y * kvreg[4 * m4 + 1] +
                   qv.z * kvreg[4 * m4 + 2] + qv.w * kvreg[4 * m4 + 3];
        }
        attn[(size_t)(nb + node) * 128 + h * 64 + lane] = (acc + xs_d) / den;
    }
}

// ---------------- GCN step: 2 nodes per wave (32 lanes x float4 each) ----------------
// 8/8/tail batched gathers; XCD-chunked swizzle for L2 locality.
template <int FIRST>
__global__ __launch_bounds__(256) void gcn_kernel(
    const float* __restrict__ xin, const float* __restrict__ attn,
    const int* __restrict__ ptr, const int2* __restrict__ ep,
    float* __restrict__ xout) {
    int bid = blockIdx.x;                                  // 8192 blocks, 8 nodes each
    int lbid = (bid & 7) * (N_NODES / 8 / 8) + (bid >> 3);
    int t = threadIdx.x;
    int n = lbid * 8 + (t >> 5);
    int lq = t & 31;
    int c4 = lq * 4;
    int cx = FIRST ? (c4 & 63) : c4;
    const int ldx = FIRST ? 64 : 128;
    int e0 = ptr[n], e1 = ptr[n + 1];
    int cnt = e1 - e0;
    float4 acc = make_float4(0.f, 0.f, 0.f, 0.f);

    {
        int2 q[8];
#pragma unroll
        for (int i = 0; i < 8; ++i) {
            int ee = e0 + i;
            if (ee > e1 - 1) ee = e1 - 1;
            if (ee < 0) ee = 0;
            q[i] = ep[ee];
        }
#pragma unroll
        for (int i = 0; i < 8; ++i) {
            float v = (i < cnt) ? __int_as_float(q[i].y) : 0.0f;
            float4 xv = *(const float4*)(xin + (size_t)q[i].x * ldx + cx);
            acc.x += v * xv.x; acc.y += v * xv.y;
            acc.z += v * xv.z; acc.w += v * xv.w;
        }
    }
    if (cnt > 8) {
        int2 q[8];
#pragma unroll
        for (int i = 0; i < 8; ++i) {
            int ee = e0 + 8 + i;
            if (ee > e1 - 1) ee = e1 - 1;
            q[i] = ep[ee];
        }
#pragma unroll
        for (int i = 0; i < 8; ++i) {
            float v = (8 + i < cnt) ? __int_as_float(q[i].y) : 0.0f;
            float4 xv = *(const float4*)(xin + (size_t)q[i].x * ldx + cx);
            acc.x += v * xv.x; acc.y += v * xv.y;
            acc.z += v * xv.z; acc.w += v * xv.w;
        }
        for (int e = e0 + 16; e < e1; ++e) {
            int2 qq = ep[e];
            float v = __int_as_float(qq.y);
            float4 xv = *(const float4*)(xin + (size_t)qq.x * ldx + cx);
            acc.x += v * xv.x; acc.y += v * xv.y;
            acc.z += v * xv.z; acc.w += v * xv.w;
        }
    }

    float4 self = *(const float4*)(xin + (size_t)n * ldx + cx);
    size_t idx = (size_t)n * 128 + c4;
    float4 at = *(const float4*)(attn + idx);
    float4 o;
    o.x = self.x + 0.5f * acc.x + 0.5f * at.x;
    o.y = self.y + 0.5f * acc.y + 0.5f * at.y;
    o.z = self.z + 0.5f * acc.z + 0.5f * at.z;
    o.w = self.w + 0.5f * acc.w + 0.5f * at.w;
    *(float4*)(xout + idx) = o;
}

// ---------------- output projection: (xs @ Wo + bo)/H ----------------
__global__ __launch_bounds__(256) void out_kernel(
    const float* __restrict__ xs, const float* __restrict__ Wo,
    const float* __restrict__ bo, float* __restrict__ out) {
    __shared__ float wlt[64 * 132];
    int t = threadIdx.x;
    for (int i = t; i < 8192; i += 256) {
        int k = i >> 6, j = i & 63;
        wlt[j * 132 + k] = Wo[i];
    }
    __syncthreads();
    int j = t & 63, ng = t >> 6;
    float bias = bo[j];
    const float* wj = wlt + j * 132;
    int nbase = blockIdx.x * 64 + ng * 16;
    for (int g = 0; g < 4; ++g) {
        int n0 = nbase + g * 4;
        const float4* xr0 = (const float4*)(xs + (size_t)(n0 + 0) * 128);
        const float4* xr1 = (const float4*)(xs + (size_t)(n0 + 1) * 128);
        const float4* xr2 = (const float4*)(xs + (size_t)(n0 + 2) * 128);
        const float4* xr3 = (const float4*)(xs + (size_t)(n0 + 3) * 128);
        float a0 = 0.f, a1 = 0.f, a2 = 0.f, a3 = 0.f;
#pragma unroll 4
        for (int k4 = 0; k4 < 32; ++k4) {
            float4 w = *(const float4*)(wj + k4 * 4);
            float4 v0 = xr0[k4], v1 = xr1[k4], v2 = xr2[k4], v3 = xr3[k4];
            a0 += w.x * v0.x + w.y * v0.y + w.z * v0.z + w.w * v0.w;
            a1 += w.x * v1.x + w.y * v1.y + w.z * v1.z + w.w * v1.w;
            a2 += w.x * v2.x + w.y * v2.y + w.z * v2.z + w.w * v2.w;
            a3 += w.x * v3.x + w.y * v3.y + w.z * v3.z + w.w * v3.w;
        }
        out[(size_t)(n0 + 0) * 64 + j] = (bias + a0) * 0.5f;
        out[(size_t)(n0 + 1) * 64 + j] = (bias + a1) * 0.5f;
        out[(size_t)(n0 + 2) * 64 + j] = (bias + a2) * 0.5f;
        out[(size_t)(n0 + 3) * 64 + j] = (bias + a3) * 0.5f;
    }
}

// ---------------- launch ----------------

extern "C" void kernel_launch(void* const* d_in, const int* in_sizes, int n_in,
                              void* d_out, int out_size, void* d_ws, size_t ws_size,
                              hipStream_t stream) {
    const float* x  = (const float*)d_in[0];
    const int* ei   = (const int*)d_in[1];
    const float* Wq = (const float*)d_in[3];
    const float* bq = (const float*)d_in[4];
    const float* Wk = (const float*)d_in[5];
    const float* bk = (const float*)d_in[6];
    const float* Wo = (const float*)d_in[7];
    const float* bo = (const float*)d_in[8];
    float* out = (float*)d_out;

    const int* row = ei;
    const int* col = ei + E_E;

    float* qs    = (float*)d_ws;                       // N*HD (later xsA)
    float* ksatt = qs + (size_t)N_NODES * HD;          // N*HD (ks, later attn)
    float* xsB   = ksatt + (size_t)N_NODES * HD;       // N*HD
    int2*  ep    = (int2*)(xsB + (size_t)N_NODES * HD);// E
    float* kvs   = (float*)(ep + E_E);                 // 32*64*64
    float* ksum  = kvs + 131072;                       // 2048
    float* xsum  = ksum + 2048;                        // 1024
    float* dinv  = xsum + 1024;                        // N
    int* degi    = (int*)(dinv + N_NODES);             // N
    int* cursor  = degi + N_NODES;                     // N (contiguous with degi)
    int* ptr     = cursor + N_NODES;                   // N+1
    int* bsums   = ptr + N_NODES + 1;                  // 256

    // one memset covers degi + cursor; one covers kvs/ksum/xsum
    hipMemsetAsync(degi, 0, (size_t)N_NODES * 2 * 4, stream);
    hipMemsetAsync(kvs, 0, (size_t)(131072 + 2048 + 1024) * 4, stream);

    deg_kernel<<<E_E / 256, 256, 0, stream>>>(col, degi);
    scan1<<<N_NODES / 256, 256, 0, stream>>>(degi, ptr, bsums, dinv);
    scan3<<<N_NODES / 256, 256, 0, stream>>>(ptr, bsums);
    scatter_kernel<<<E_E / 256, 256, 0, stream>>>(row, col, ptr, cursor, dinv, ep);

    proj_kernel<<<2048, 256, 0, stream>>>(x, Wq, bq, Wk, bk, qs, ksatt);

    kvs_kernel<<<1024, 256, 0, stream>>>(ksatt, x, kvs, ksum, xsum);
    attn_kernel<<<1024, 256, 0, stream>>>(qs, kvs, ksum, xsum, ksatt);

    gcn_kernel<1><<<N_NODES / 8, 256, 0, stream>>>(x, ksatt, ptr, ep, qs);
    gcn_kernel<0><<<N_NODES / 8, 256, 0, stream>>>(qs, ksatt, ptr, ep, xsB);
    gcn_kernel<0><<<N_NODES / 8, 256, 0, stream>>>(xsB, ksatt, ptr, ep, qs);
    gcn_kernel<0><<<N_NODES / 8, 256, 0, stream>>>(qs, ksatt, ptr, ep, xsB);

    out_kernel<<<1024, 256, 0, stream>>>(xsB, Wo, bo, out);
}

// Round 8
// 476.721 us; speedup vs baseline: 1.1880x; 1.1880x over previous
//
#include <hip/hip_runtime.h>

#define N_NODES 65536
#define B_G     16
#define NPG_    4096
#define H_H     2
#define D_D     64
#define HD      128
#define E_E     524288
#define D_OUT   64

// ---------------- degree / CSR build ----------------

__global__ void deg_kernel(const int* __restrict__ col, int* __restrict__ degi) {
    int e = blockIdx.x * 256 + threadIdx.x;
    if (e < E_E) atomicAdd(&degi[col[e]], 1);
}

// block-local exclusive scan of degrees; also emits dinv = deg^-1/2 (fused).
__global__ void scan1(const int* __restrict__ degi, int* __restrict__ ptr,
                      int* __restrict__ bsums, float* __restrict__ dinv) {
    __shared__ int lds[256];
    int t = threadIdx.x;
    int i = blockIdx.x * 256 + t;
    int v = degi[i];
    dinv[i] = (v > 0) ? (1.0f / sqrtf((float)v)) : 0.0f;
    lds[t] = v;
    __syncthreads();
    for (int off = 1; off < 256; off <<= 1) {
        int tmp = (t >= off) ? lds[t - off] : 0;
        __syncthreads();
        lds[t] += tmp;
        __syncthreads();
    }
    ptr[i] = lds[t] - v;
    if (t == 255) bsums[blockIdx.x] = lds[255];
}

// adds prefix of bsums[0..bid-1] (computed in-block; absorbs old scan2).
__global__ void scan3(int* __restrict__ ptr, const int* __restrict__ bsums) {
    __shared__ int red[256];
    int t = threadIdx.x;
    red[t] = (t < (int)blockIdx.x) ? bsums[t] : 0;
    __syncthreads();
    for (int off = 128; off > 0; off >>= 1) {
        if (t < off) red[t] += red[t + off];
        __syncthreads();
    }
    int i = blockIdx.x * 256 + t;
    ptr[i] += red[0];
    if (i == 0) ptr[N_NODES] = E_E;
}

__global__ void scatter_kernel(const int* __restrict__ row, const int* __restrict__ col,
                               const int* __restrict__ ptr, int* __restrict__ cursor,
                               const float* __restrict__ dinv,
                               int2* __restrict__ ep) {
    int e = blockIdx.x * 256 + threadIdx.x;
    if (e < E_E) {
        int c = col[e], r = row[e];
        int p = ptr[c] + atomicAdd(&cursor[c], 1);
        ep[p] = make_int2(r, __float_as_int(dinv[c] * dinv[r]));
    }
}

// ---------------- q/k projection + fused L2-normalize ----------------
// Register-blocked LDS GEMM: thread = 4 nodes x 8 cols (cols strided 16 so
// concurrent lane reads hit consecutive float4s -> 2-way/free). wt4[k4][col]
// float4 packing is 16B-aligned by construction (stride-65 scalar trap from
// R6/R7 eliminated). Per k4: 12 ds_read_b128 (144 cyc) vs 128 FMA (256 cyc)
// -> FMA-bound. grid 2048: bid&1 = q/k, 64 nodes/block.
__global__ __launch_bounds__(256) void proj_kernel(
    const float* __restrict__ x,
    const float* __restrict__ Wq, const float* __restrict__ bq,
    const float* __restrict__ Wk, const float* __restrict__ bk,
    float* __restrict__ qs, float* __restrict__ ks) {
    __shared__ float4 wt4[16 * 128];   // [k4][col] : W[4k4..4k4+3][col]
    __shared__ float4 xt4[64 * 17];    // [node][k4] padded 16->17
    __shared__ float bl[128];
    int t = threadIdx.x;
    int qk = blockIdx.x & 1;
    int nb = (blockIdx.x >> 1) * 64;
    const float* W = qk ? Wk : Wq;
    const float* bias = qk ? bk : bq;
    float* outp = qk ? ks : qs;

    // stage W -> wt4 (gather 4 k-rows per col; W L1-resident after 1st block)
    for (int i = t; i < 2048; i += 256) {
        int k4 = i >> 7, c = i & 127;
        wt4[i] = make_float4(W[(4 * k4 + 0) * 128 + c], W[(4 * k4 + 1) * 128 + c],
                             W[(4 * k4 + 2) * 128 + c], W[(4 * k4 + 3) * 128 + c]);
    }
    // stage x -> xt4 (coalesced float4)
    const float4* xg = (const float4*)(x + (size_t)nb * 64);
    for (int i = t; i < 1024; i += 256) {
        int node = i >> 4, k4 = i & 15;
        xt4[node * 17 + k4] = xg[i];
    }
    if (t < 128) bl[t] = bias[t];
    __syncthreads();

    int cg = t & 15;            // col group: cols cg + 16j
    int nd = (t >> 4) & 3;      // node sub-group
    int w = t >> 6;             // wave
    int n_t = w * 16 + nd * 4;  // first of 4 nodes

    float acc[4][8];
#pragma unroll
    for (int i = 0; i < 4; ++i)
#pragma unroll
        for (int j = 0; j < 8; ++j) acc[i][j] = 0.f;

#pragma unroll 2
    for (int k4 = 0; k4 < 16; ++k4) {
        float4 xv0 = xt4[(n_t + 0) * 17 + k4];
        float4 xv1 = xt4[(n_t + 1) * 17 + k4];
        float4 xv2 = xt4[(n_t + 2) * 17 + k4];
        float4 xv3 = xt4[(n_t + 3) * 17 + k4];
#pragma unroll
        for (int j = 0; j < 8; ++j) {
            float4 wv = wt4[k4 * 128 + cg + 16 * j];
            acc[0][j] += wv.x * xv0.x + wv.y * xv0.y + wv.z * xv0.z + wv.w * xv0.w;
            acc[1][j] += wv.x * xv1.x + wv.y * xv1.y + wv.z * xv1.z + wv.w * xv1.w;
            acc[2][j] += wv.x * xv2.x + wv.y * xv2.y + wv.z * xv2.z + wv.w * xv2.w;
            acc[3][j] += wv.x * xv3.x + wv.y * xv3.y + wv.z * xv3.z + wv.w * xv3.w;
        }
    }

    float bcol[8];
#pragma unroll
    for (int j = 0; j < 8; ++j) bcol[j] = bl[cg + 16 * j];

#pragma unroll
    for (int i = 0; i < 4; ++i) {
#pragma unroll
        for (int j = 0; j < 8; ++j) acc[i][j] += bcol[j];
        // head0 = j 0..3 (cols 0..63), head1 = j 4..7
        float s0 = acc[i][0] * acc[i][0] + acc[i][1] * acc[i][1] +
                   acc[i][2] * acc[i][2] + acc[i][3] * acc[i][3];
        float s1 = acc[i][4] * acc[i][4] + acc[i][5] * acc[i][5] +
                   acc[i][6] * acc[i][6] + acc[i][7] * acc[i][7];
#pragma unroll
        for (int off = 8; off > 0; off >>= 1) {   // reduce over 16 cg lanes
            s0 += __shfl_xor(s0, off);
            s1 += __shfl_xor(s1, off);
        }
        float r0 = rsqrtf(s0), r1 = rsqrtf(s1);
        size_t base = (size_t)(nb + n_t + i) * 128 + cg;
#pragma unroll
        for (int j = 0; j < 4; ++j) outp[base + 16 * j] = acc[i][j] * r0;
#pragma unroll
        for (int j = 4; j < 8; ++j) outp[base + 16 * j] = acc[i][j] * r1;
    }
}

// ---------------- kvs = K^T X per (b,h); plus ksum, xsum ----------------
// 1024 blocks: (bh, 32 chunks of 128 nodes) -> 4 blocks/CU.
__global__ __launch_bounds__(256) void kvs_kernel(
    const float* __restrict__ ks, const float* __restrict__ x,
    float* __restrict__ kvs, float* __restrict__ ksum, float* __restrict__ xsum) {
    int bid = blockIdx.x;
    int chunk = bid & 31;
    int bh = bid >> 5;
    int b = bh >> 1, h = bh & 1;
    int t = threadIdx.x;
    int mrow = t >> 4, dcol = t & 15;
    int m0 = mrow * 4, d0 = dcol * 4;
    __shared__ float kl[32 * 64];
    __shared__ float xl[32 * 64];
    float acc[4][4] = {{0}};
    float ksacc[4] = {0, 0, 0, 0};
    float xsacc[4] = {0, 0, 0, 0};
    int node0 = b * NPG_ + chunk * 128;
    for (int s = 0; s < 4; ++s) {
        int nb = node0 + s * 32;
        for (int i = t; i < 512; i += 256) {
            int l = i >> 4, q = i & 15;
            ((float4*)kl)[i] = *(const float4*)(ks + (size_t)(nb + l) * 128 + h * 64 + q * 4);
        }
        const float4* xg = (const float4*)(x + (size_t)nb * 64);
        for (int i = t; i < 512; i += 256) ((float4*)xl)[i] = xg[i];
        __syncthreads();
        for (int l = 0; l < 32; ++l) {
            float4 kv = *(float4*)(kl + l * 64 + m0);
            float4 xv = *(float4*)(xl + l * 64 + d0);
            float kk[4] = {kv.x, kv.y, kv.z, kv.w};
            float xx[4] = {xv.x, xv.y, xv.z, xv.w};
#pragma unroll
            for (int i = 0; i < 4; ++i)
#pragma unroll
                for (int j = 0; j < 4; ++j) acc[i][j] += kk[i] * xx[j];
            if (dcol == 0) {
#pragma unroll
                for (int i = 0; i < 4; ++i) ksacc[i] += kk[i];
            }
            if (mrow == 0) {
#pragma unroll
                for (int j = 0; j < 4; ++j) xsacc[j] += xx[j];
            }
        }
        __syncthreads();
    }
#pragma unroll
    for (int i = 0; i < 4; ++i)
#pragma unroll
        for (int j = 0; j < 4; ++j)
            atomicAdd(&kvs[(bh * 64 + m0 + i) * 64 + d0 + j], acc[i][j]);
    if (dcol == 0) {
#pragma unroll
        for (int i = 0; i < 4; ++i) atomicAdd(&ksum[bh * 64 + m0 + i], ksacc[i]);
    }
    if (mrow == 0 && h == 0) {
#pragma unroll
        for (int j = 0; j < 4; ++j) atomicAdd(&xsum[b * 64 + d0 + j], xsacc[j]);
    }
}

// ---------------- attention output: block = 128 nodes x 1 head ----------------
__global__ __launch_bounds__(256) void attn_kernel(
    const float* __restrict__ qs, const float* __restrict__ kvs,
    const float* __restrict__ ksum, const float* __restrict__ xsum,
    float* __restrict__ attn) {
    __shared__ float ql[128 * 64];
    int bid = blockIdx.x;
    int h = bid & 1;
    int nb = (bid >> 1) * 128;
    int b = nb >> 12;
    int bh = b * 2 + h;
    int t = threadIdx.x;
    int lane = t & 63;
    for (int i = t; i < 128 * 16; i += 256) {
        int r = i >> 4, q4 = i & 15;
        ((float4*)ql)[i] = *(const float4*)(qs + (size_t)(nb + r) * 128 + h * 64 + q4 * 4);
    }
    float kvreg[64];
    const float* kvp = kvs + bh * 4096 + lane;
#pragma unroll
    for (int m = 0; m < 64; ++m) kvreg[m] = kvp[m * 64];
    float ksreg = ksum[bh * 64 + lane];
    float xs_d = xsum[b * 64 + lane];
    __syncthreads();
    int nslot = t >> 6;
    for (int nn = 0; nn < 32; ++nn) {
        int node = nn * 4 + nslot;
        const float* qrow = ql + node * 64;
        float p = qrow[lane] * ksreg;
#pragma unroll
        for (int off = 32; off > 0; off >>= 1) p += __shfl_xor(p, off);
        float den = p + 16.0f;
        float acc = 0.f;
#pragma unroll
        for (int m4 = 0; m4 < 16; ++m4) {
            float4 qv = *(const float4*)(qrow + m4 * 4);
            acc += qv.x * kvreg[4 * m4] + qv.y * kvreg[4 * m4 + 1] +
                   qv.z * kvreg[4 * m4 + 2] + qv.w * kvreg[4 * m4 + 3];
        }
        attn[(size_t)(nb + node) * 128 + h * 64 + lane] = (acc + xs_d) / den;
    }
}

// ---------------- GCN step: 2 nodes per wave (32 lanes x float4 each) ----------------
// 8/8/tail batched gathers; XCD-chunked swizzle for L2 locality.
template <int FIRST>
__global__ __launch_bounds__(256) void gcn_kernel(
    const float* __restrict__ xin, const float* __restrict__ attn,
    const int* __restrict__ ptr, const int2* __restrict__ ep,
    float* __restrict__ xout) {
    int bid = blockIdx.x;                                  // 8192 blocks, 8 nodes each
    int lbid = (bid & 7) * (N_NODES / 8 / 8) + (bid >> 3);
    int t = threadIdx.x;
    int n = lbid * 8 + (t >> 5);
    int lq = t & 31;
    int c4 = lq * 4;
    int cx = FIRST ? (c4 & 63) : c4;
    const int ldx = FIRST ? 64 : 128;
    int e0 = ptr[n], e1 = ptr[n + 1];
    int cnt = e1 - e0;
    float4 acc = make_float4(0.f, 0.f, 0.f, 0.f);

    {
        int2 q[8];
#pragma unroll
        for (int i = 0; i < 8; ++i) {
            int ee = e0 + i;
            if (ee > e1 - 1) ee = e1 - 1;
            if (ee < 0) ee = 0;
            q[i] = ep[ee];
        }
#pragma unroll
        for (int i = 0; i < 8; ++i) {
            float v = (i < cnt) ? __int_as_float(q[i].y) : 0.0f;
            float4 xv = *(const float4*)(xin + (size_t)q[i].x * ldx + cx);
            acc.x += v * xv.x; acc.y += v * xv.y;
            acc.z += v * xv.z; acc.w += v * xv.w;
        }
    }
    if (cnt > 8) {
        int2 q[8];
#pragma unroll
        for (int i = 0; i < 8; ++i) {
            int ee = e0 + 8 + i;
            if (ee > e1 - 1) ee = e1 - 1;
            q[i] = ep[ee];
        }
#pragma unroll
        for (int i = 0; i < 8; ++i) {
            float v = (8 + i < cnt) ? __int_as_float(q[i].y) : 0.0f;
            float4 xv = *(const float4*)(xin + (size_t)q[i].x * ldx + cx);
            acc.x += v * xv.x; acc.y += v * xv.y;
            acc.z += v * xv.z; acc.w += v * xv.w;
        }
        for (int e = e0 + 16; e < e1; ++e) {
            int2 qq = ep[e];
            float v = __int_as_float(qq.y);
            float4 xv = *(const float4*)(xin + (size_t)qq.x * ldx + cx);
            acc.x += v * xv.x; acc.y += v * xv.y;
            acc.z += v * xv.z; acc.w += v * xv.w;
        }
    }

    float4 self = *(const float4*)(xin + (size_t)n * ldx + cx);
    size_t idx = (size_t)n * 128 + c4;
    float4 at = *(const float4*)(attn + idx);
    float4 o;
    o.x = self.x + 0.5f * acc.x + 0.5f * at.x;
    o.y = self.y + 0.5f * acc.y + 0.5f * at.y;
    o.z = self.z + 0.5f * acc.z + 0.5f * at.z;
    o.w = self.w + 0.5f * acc.w + 0.5f * at.w;
    *(float4*)(xout + idx) = o;
}

// ---------------- output projection: (xs @ Wo + bo)/H ----------------
__global__ __launch_bounds__(256) void out_kernel(
    const float* __restrict__ xs, const float* __restrict__ Wo,
    const float* __restrict__ bo, float* __restrict__ out) {
    __shared__ float wlt[64 * 132];
    int t = threadIdx.x;
    for (int i = t; i < 8192; i += 256) {
        int k = i >> 6, j = i & 63;
        wlt[j * 132 + k] = Wo[i];
    }
    __syncthreads();
    int j = t & 63, ng = t >> 6;
    float bias = bo[j];
    const float* wj = wlt + j * 132;
    int nbase = blockIdx.x * 64 + ng * 16;
    for (int g = 0; g < 4; ++g) {
        int n0 = nbase + g * 4;
        const float4* xr0 = (const float4*)(xs + (size_t)(n0 + 0) * 128);
        const float4* xr1 = (const float4*)(xs + (size_t)(n0 + 1) * 128);
        const float4* xr2 = (const float4*)(xs + (size_t)(n0 + 2) * 128);
        const float4* xr3 = (const float4*)(xs + (size_t)(n0 + 3) * 128);
        float a0 = 0.f, a1 = 0.f, a2 = 0.f, a3 = 0.f;
#pragma unroll 4
        for (int k4 = 0; k4 < 32; ++k4) {
            float4 w = *(const float4*)(wj + k4 * 4);
            float4 v0 = xr0[k4], v1 = xr1[k4], v2 = xr2[k4], v3 = xr3[k4];
            a0 += w.x * v0.x + w.y * v0.y + w.z * v0.z + w.w * v0.w;
            a1 += w.x * v1.x + w.y * v1.y + w.z * v1.z + w.w * v1.w;
            a2 += w.x * v2.x + w.y * v2.y + w.z * v2.z + w.w * v2.w;
            a3 += w.x * v3.x + w.y * v3.y + w.z * v3.z + w.w * v3.w;
        }
        out[(size_t)(n0 + 0) * 64 + j] = (bias + a0) * 0.5f;
        out[(size_t)(n0 + 1) * 64 + j] = (bias + a1) * 0.5f;
        out[(size_t)(n0 + 2) * 64 + j] = (bias + a2) * 0.5f;
        out[(size_t)(n0 + 3) * 64 + j] = (bias + a3) * 0.5f;
    }
}

// ---------------- launch ----------------

extern "C" void kernel_launch(void* const* d_in, const int* in_sizes, int n_in,
                              void* d_out, int out_size, void* d_ws, size_t ws_size,
                              hipStream_t stream) {
    const float* x  = (const float*)d_in[0];
    const int* ei   = (const int*)d_in[1];
    const float* Wq = (const float*)d_in[3];
    const float* bq = (const float*)d_in[4];
    const float* Wk = (const float*)d_in[5];
    const float* bk = (const float*)d_in[6];
    const float* Wo = (const float*)d_in[7];
    const float* bo = (const float*)d_in[8];
    float* out = (float*)d_out;

    const int* row = ei;
    const int* col = ei + E_E;

    float* qs    = (float*)d_ws;                       // N*HD (later xsA)
    float* ksatt = qs + (size_t)N_NODES * HD;          // N*HD (ks, later attn)
    float* xsB   = ksatt + (size_t)N_NODES * HD;       // N*HD
    int2*  ep    = (int2*)(xsB + (size_t)N_NODES * HD);// E
    float* kvs   = (float*)(ep + E_E);                 // 32*64*64
    float* ksum  = kvs + 131072;                       // 2048
    float* xsum  = ksum + 2048;                        // 1024
    float* dinv  = xsum + 1024;                        // N
    int* degi    = (int*)(dinv + N_NODES);             // N
    int* cursor  = degi + N_NODES;                     // N (contiguous with degi)
    int* ptr     = cursor + N_NODES;                   // N+1
    int* bsums   = ptr + N_NODES + 1;                  // 256

    hipMemsetAsync(degi, 0, (size_t)N_NODES * 2 * 4, stream);
    hipMemsetAsync(kvs, 0, (size_t)(131072 + 2048 + 1024) * 4, stream);

    deg_kernel<<<E_E / 256, 256, 0, stream>>>(col, degi);
    scan1<<<N_NODES / 256, 256, 0, stream>>>(degi, ptr, bsums, dinv);
    scan3<<<N_NODES / 256, 256, 0, stream>>>(ptr, bsums);
    scatter_kernel<<<E_E / 256, 256, 0, stream>>>(row, col, ptr, cursor, dinv, ep);

    proj_kernel<<<2048, 256, 0, stream>>>(x, Wq, bq, Wk, bk, qs, ksatt);

    kvs_kernel<<<1024, 256, 0, stream>>>(ksatt, x, kvs, ksum, xsum);
    attn_kernel<<<1024, 256, 0, stream>>>(qs, kvs, ksum, xsum, ksatt);

    gcn_kernel<1><<<N_NODES / 8, 256, 0, stream>>>(x, ksatt, ptr, ep, qs);
    gcn_kernel<0><<<N_NODES / 8, 256, 0, stream>>>(qs, ksatt, ptr, ep, xsB);
    gcn_kernel<0><<<N_NODES / 8, 256, 0, stream>>>(xsB, ksatt, ptr, ep, qs);
    gcn_kernel<0><<<N_NODES / 8, 256, 0, stream>>>(qs, ksatt, ptr, ep, xsB);

    out_kernel<<<1024, 256, 0, stream>>>(xsB, Wo, bo, out);
}

// Round 9
// 419.090 us; speedup vs baseline: 1.3514x; 1.1375x over previous
//
#include <hip/hip_runtime.h>

#define N_NODES 65536
#define B_G     16
#define NPG_    4096
#define H_H     2
#define D_D     64
#define HD      128
#define E_E     524288
#define D_OUT   64

// ---------------- degree / CSR build ----------------

__global__ void deg_kernel(const int* __restrict__ col, int* __restrict__ degi) {
    int e = blockIdx.x * 256 + threadIdx.x;
    if (e < E_E) atomicAdd(&degi[col[e]], 1);
}

__global__ void scan1(const int* __restrict__ degi, int* __restrict__ ptr,
                      int* __restrict__ bsums, float* __restrict__ dinv) {
    __shared__ int lds[256];
    int t = threadIdx.x;
    int i = blockIdx.x * 256 + t;
    int v = degi[i];
    dinv[i] = (v > 0) ? (1.0f / sqrtf((float)v)) : 0.0f;
    lds[t] = v;
    __syncthreads();
    for (int off = 1; off < 256; off <<= 1) {
        int tmp = (t >= off) ? lds[t - off] : 0;
        __syncthreads();
        lds[t] += tmp;
        __syncthreads();
    }
    ptr[i] = lds[t] - v;
    if (t == 255) bsums[blockIdx.x] = lds[255];
}

__global__ void scan3(int* __restrict__ ptr, const int* __restrict__ bsums) {
    __shared__ int red[256];
    int t = threadIdx.x;
    red[t] = (t < (int)blockIdx.x) ? bsums[t] : 0;
    __syncthreads();
    for (int off = 128; off > 0; off >>= 1) {
        if (t < off) red[t] += red[t + off];
        __syncthreads();
    }
    int i = blockIdx.x * 256 + t;
    ptr[i] += red[0];
    if (i == 0) ptr[N_NODES] = E_E;
}

__global__ void scatter_kernel(const int* __restrict__ row, const int* __restrict__ col,
                               const int* __restrict__ ptr, int* __restrict__ cursor,
                               const float* __restrict__ dinv,
                               int2* __restrict__ ep) {
    int e = blockIdx.x * 256 + threadIdx.x;
    if (e < E_E) {
        int c = col[e], r = row[e];
        int p = ptr[c] + atomicAdd(&cursor[c], 1);
        ep[p] = make_int2(r, __float_as_int(dinv[c] * dinv[r]));
    }
}

// ---------------- q/k projection + fused L2-normalize (R8, proven) ----------------
__global__ __launch_bounds__(256) void proj_kernel(
    const float* __restrict__ x,
    const float* __restrict__ Wq, const float* __restrict__ bq,
    const float* __restrict__ Wk, const float* __restrict__ bk,
    float* __restrict__ qs, float* __restrict__ ks) {
    __shared__ float4 wt4[16 * 128];
    __shared__ float4 xt4[64 * 17];
    __shared__ float bl[128];
    int t = threadIdx.x;
    int qk = blockIdx.x & 1;
    int nb = (blockIdx.x >> 1) * 64;
    const float* W = qk ? Wk : Wq;
    const float* bias = qk ? bk : bq;
    float* outp = qk ? ks : qs;

    for (int i = t; i < 2048; i += 256) {
        int k4 = i >> 7, c = i & 127;
        wt4[i] = make_float4(W[(4 * k4 + 0) * 128 + c], W[(4 * k4 + 1) * 128 + c],
                             W[(4 * k4 + 2) * 128 + c], W[(4 * k4 + 3) * 128 + c]);
    }
    const float4* xg = (const float4*)(x + (size_t)nb * 64);
    for (int i = t; i < 1024; i += 256) {
        int node = i >> 4, k4 = i & 15;
        xt4[node * 17 + k4] = xg[i];
    }
    if (t < 128) bl[t] = bias[t];
    __syncthreads();

    int cg = t & 15;
    int nd = (t >> 4) & 3;
    int w = t >> 6;
    int n_t = w * 16 + nd * 4;

    float acc[4][8];
#pragma unroll
    for (int i = 0; i < 4; ++i)
#pragma unroll
        for (int j = 0; j < 8; ++j) acc[i][j] = 0.f;

#pragma unroll 2
    for (int k4 = 0; k4 < 16; ++k4) {
        float4 xv0 = xt4[(n_t + 0) * 17 + k4];
        float4 xv1 = xt4[(n_t + 1) * 17 + k4];
        float4 xv2 = xt4[(n_t + 2) * 17 + k4];
        float4 xv3 = xt4[(n_t + 3) * 17 + k4];
#pragma unroll
        for (int j = 0; j < 8; ++j) {
            float4 wv = wt4[k4 * 128 + cg + 16 * j];
            acc[0][j] += wv.x * xv0.x + wv.y * xv0.y + wv.z * xv0.z + wv.w * xv0.w;
            acc[1][j] += wv.x * xv1.x + wv.y * xv1.y + wv.z * xv1.z + wv.w * xv1.w;
            acc[2][j] += wv.x * xv2.x + wv.y * xv2.y + wv.z * xv2.z + wv.w * xv2.w;
            acc[3][j] += wv.x * xv3.x + wv.y * xv3.y + wv.z * xv3.z + wv.w * xv3.w;
        }
    }

    float bcol[8];
#pragma unroll
    for (int j = 0; j < 8; ++j) bcol[j] = bl[cg + 16 * j];

#pragma unroll
    for (int i = 0; i < 4; ++i) {
#pragma unroll
        for (int j = 0; j < 8; ++j) acc[i][j] += bcol[j];
        float s0 = acc[i][0] * acc[i][0] + acc[i][1] * acc[i][1] +
                   acc[i][2] * acc[i][2] + acc[i][3] * acc[i][3];
        float s1 = acc[i][4] * acc[i][4] + acc[i][5] * acc[i][5] +
                   acc[i][6] * acc[i][6] + acc[i][7] * acc[i][7];
#pragma unroll
        for (int off = 8; off > 0; off >>= 1) {
            s0 += __shfl_xor(s0, off);
            s1 += __shfl_xor(s1, off);
        }
        float r0 = rsqrtf(s0), r1 = rsqrtf(s1);
        size_t base = (size_t)(nb + n_t + i) * 128 + cg;
#pragma unroll
        for (int j = 0; j < 4; ++j) outp[base + 16 * j] = acc[i][j] * r0;
#pragma unroll
        for (int j = 4; j < 8; ++j) outp[base + 16 * j] = acc[i][j] * r1;
    }
}

// ---------------- kvs stage A: per-block partials (no atomics) ----------------
// 1024 blocks: (bh, 32 chunks of 128 nodes); block stores its 64x64 partial.
__global__ __launch_bounds__(256) void kvs_part(
    const float* __restrict__ ks, const float* __restrict__ x,
    float* __restrict__ partials, float* __restrict__ ksum, float* __restrict__ xsum) {
    int bid = blockIdx.x;
    int chunk = bid & 31;
    int bh = bid >> 5;
    int b = bh >> 1, h = bh & 1;
    int t = threadIdx.x;
    int mrow = t >> 4, dcol = t & 15;
    int m0 = mrow * 4, d0 = dcol * 4;
    __shared__ float kl[32 * 64];
    __shared__ float xl[32 * 64];
    float acc[4][4] = {{0}};
    float ksacc[4] = {0, 0, 0, 0};
    float xsacc[4] = {0, 0, 0, 0};
    int node0 = b * NPG_ + chunk * 128;
    for (int s = 0; s < 4; ++s) {
        int nb = node0 + s * 32;
        for (int i = t; i < 512; i += 256) {
            int l = i >> 4, q = i & 15;
            ((float4*)kl)[i] = *(const float4*)(ks + (size_t)(nb + l) * 128 + h * 64 + q * 4);
        }
        const float4* xg = (const float4*)(x + (size_t)nb * 64);
        for (int i = t; i < 512; i += 256) ((float4*)xl)[i] = xg[i];
        __syncthreads();
        for (int l = 0; l < 32; ++l) {
            float4 kv = *(float4*)(kl + l * 64 + m0);
            float4 xv = *(float4*)(xl + l * 64 + d0);
            float kk[4] = {kv.x, kv.y, kv.z, kv.w};
            float xx[4] = {xv.x, xv.y, xv.z, xv.w};
#pragma unroll
            for (int i = 0; i < 4; ++i)
#pragma unroll
                for (int j = 0; j < 4; ++j) acc[i][j] += kk[i] * xx[j];
            if (dcol == 0) {
#pragma unroll
                for (int i = 0; i < 4; ++i) ksacc[i] += kk[i];
            }
            if (mrow == 0) {
#pragma unroll
                for (int j = 0; j < 4; ++j) xsacc[j] += xx[j];
            }
        }
        __syncthreads();
    }
    float* pout = partials + (size_t)bid * 4096;
#pragma unroll
    for (int i = 0; i < 4; ++i)
        *(float4*)(pout + (m0 + i) * 64 + d0) =
            make_float4(acc[i][0], acc[i][1], acc[i][2], acc[i][3]);
    if (dcol == 0) {
#pragma unroll
        for (int i = 0; i < 4; ++i) atomicAdd(&ksum[bh * 64 + m0 + i], ksacc[i]);
    }
    if (mrow == 0 && h == 0) {
#pragma unroll
        for (int j = 0; j < 4; ++j) atomicAdd(&xsum[b * 64 + d0 + j], xsacc[j]);
    }
}

// ---------------- kvs stage B: reduce 32 chunk-partials ----------------
__global__ __launch_bounds__(256) void kvs_reduce(
    const float* __restrict__ partials, float* __restrict__ kvs) {
    int i = blockIdx.x * 256 + threadIdx.x;   // bh*4096 + elem
    int bh = i >> 12, elem = i & 4095;
    const float* p = partials + (size_t)bh * 32 * 4096 + elem;
    float s = 0.f;
#pragma unroll
    for (int c = 0; c < 32; ++c) s += p[c * 4096];
    kvs[i] = s;
}

// ---------------- attention output: block = 128 nodes x 1 head ----------------
__global__ __launch_bounds__(256) void attn_kernel(
    const float* __restrict__ qs, const float* __restrict__ kvs,
    const float* __restrict__ ksum, const float* __restrict__ xsum,
    float* __restrict__ attn) {
    __shared__ float ql[128 * 64];
    int bid = blockIdx.x;
    int h = bid & 1;
    int nb = (bid >> 1) * 128;
    int b = nb >> 12;
    int bh = b * 2 + h;
    int t = threadIdx.x;
    int lane = t & 63;
    for (int i = t; i < 128 * 16; i += 256) {
        int r = i >> 4, q4 = i & 15;
        ((float4*)ql)[i] = *(const float4*)(qs + (size_t)(nb + r) * 128 + h * 64 + q4 * 4);
    }
    float kvreg[64];
    const float* kvp = kvs + bh * 4096 + lane;
#pragma unroll
    for (int m = 0; m < 64; ++m) kvreg[m] = kvp[m * 64];
    float ksreg = ksum[bh * 64 + lane];
    float xs_d = xsum[b * 64 + lane];
    __syncthreads();
    int nslot = t >> 6;
    for (int nn = 0; nn < 32; ++nn) {
        int node = nn * 4 + nslot;
        const float* qrow = ql + node * 64;
        float p = qrow[lane] * ksreg;
#pragma unroll
        for (int off = 32; off > 0; off >>= 1) p += __shfl_xor(p, off);
        float den = p + 16.0f;
        float acc = 0.f;
#pragma unroll
        for (int m4 = 0; m4 < 16; ++m4) {
            float4 qv = *(const float4*)(qrow + m4 * 4);
            acc += qv.x * kvreg[4 * m4] + qv.y * kvreg[4 * m4 + 1] +
                   qv.z * kvreg[4 * m4 + 2] + qv.w * kvreg[4 * m4 + 3];
        }
        attn[(size_t)(nb + node) * 128 + h * 64 + lane] = (acc + xs_d) / den;
    }
}

// ---------------- a = attn @ Wo  (out_kernel structure, no bias/scale) ----------------
__global__ __launch_bounds__(256) void awo_kernel(
    const float* __restrict__ attn, const float* __restrict__ Wo,
    float* __restrict__ a) {
    __shared__ float wlt[64 * 132];
    int t = threadIdx.x;
    for (int i = t; i < 8192; i += 256) {
        int k = i >> 6, j = i & 63;
        wlt[j * 132 + k] = Wo[i];
    }
    __syncthreads();
    int j = t & 63, ng = t >> 6;
    const float* wj = wlt + j * 132;
    int nbase = blockIdx.x * 64 + ng * 16;
    for (int g = 0; g < 4; ++g) {
        int n0 = nbase + g * 4;
        const float4* xr0 = (const float4*)(attn + (size_t)(n0 + 0) * 128);
        const float4* xr1 = (const float4*)(attn + (size_t)(n0 + 1) * 128);
        const float4* xr2 = (const float4*)(attn + (size_t)(n0 + 2) * 128);
        const float4* xr3 = (const float4*)(attn + (size_t)(n0 + 3) * 128);
        float a0 = 0.f, a1 = 0.f, a2 = 0.f, a3 = 0.f;
#pragma unroll 4
        for (int k4 = 0; k4 < 32; ++k4) {
            float4 w = *(const float4*)(wj + k4 * 4);
            float4 v0 = xr0[k4], v1 = xr1[k4], v2 = xr2[k4], v3 = xr3[k4];
            a0 += w.x * v0.x + w.y * v0.y + w.z * v0.z + w.w * v0.w;
            a1 += w.x * v1.x + w.y * v1.y + w.z * v1.z + w.w * v1.w;
            a2 += w.x * v2.x + w.y * v2.y + w.z * v2.z + w.w * v2.w;
            a3 += w.x * v3.x + w.y * v3.y + w.z * v3.z + w.w * v3.w;
        }
        a[(size_t)(n0 + 0) * 64 + j] = a0;
        a[(size_t)(n0 + 1) * 64 + j] = a1;
        a[(size_t)(n0 + 2) * 64 + j] = a2;
        a[(size_t)(n0 + 3) * 64 + j] = a3;
    }
}

// ---------------- y0 = x @ (Wo_top + Wo_bot)  (K=64) ----------------
__global__ __launch_bounds__(256) void y0_kernel(
    const float* __restrict__ x, const float* __restrict__ Wo,
    float* __restrict__ y0) {
    __shared__ float wl[64 * 68];
    int t = threadIdx.x;
    for (int i = t; i < 4096; i += 256) {
        int k = i >> 6, j = i & 63;
        wl[j * 68 + k] = Wo[k * 64 + j] + Wo[(k + 64) * 64 + j];
    }
    __syncthreads();
    int j = t & 63, ng = t >> 6;
    const float* wj = wl + j * 68;
    int nbase = blockIdx.x * 64 + ng * 16;
    for (int g = 0; g < 4; ++g) {
        int n0 = nbase + g * 4;
        const float4* xr0 = (const float4*)(x + (size_t)(n0 + 0) * 64);
        const float4* xr1 = (const float4*)(x + (size_t)(n0 + 1) * 64);
        const float4* xr2 = (const float4*)(x + (size_t)(n0 + 2) * 64);
        const float4* xr3 = (const float4*)(x + (size_t)(n0 + 3) * 64);
        float a0 = 0.f, a1 = 0.f, a2 = 0.f, a3 = 0.f;
#pragma unroll 4
        for (int k4 = 0; k4 < 16; ++k4) {
            float4 w = *(const float4*)(wj + k4 * 4);
            float4 v0 = xr0[k4], v1 = xr1[k4], v2 = xr2[k4], v3 = xr3[k4];
            a0 += w.x * v0.x + w.y * v0.y + w.z * v0.z + w.w * v0.w;
            a1 += w.x * v1.x + w.y * v1.y + w.z * v1.z + w.w * v1.w;
            a2 += w.x * v2.x + w.y * v2.y + w.z * v2.z + w.w * v2.w;
            a3 += w.x * v3.x + w.y * v3.y + w.z * v3.z + w.w * v3.w;
        }
        y0[(size_t)(n0 + 0) * 64 + j] = a0;
        y0[(size_t)(n0 + 1) * 64 + j] = a1;
        y0[(size_t)(n0 + 2) * 64 + j] = a2;
        y0[(size_t)(n0 + 3) * 64 + j] = a3;
    }
}

// ---------------- GCN step in 64-col space: 4 nodes/wave, 16 lanes x float4 ----------------
// y' = y + 0.5*A y + 0.5*a ; LAST fuses (+bo)*0.5 and writes d_out.
template <int LAST>
__global__ __launch_bounds__(256) void gcn64_kernel(
    const float* __restrict__ yin, const float* __restrict__ a,
    const int* __restrict__ ptr, const int2* __restrict__ ep,
    float* __restrict__ yout, const float* __restrict__ bo) {
    int bid = blockIdx.x;                                  // 4096 blocks, 16 nodes each
    int lbid = (bid & 7) * (N_NODES / 16 / 8) + (bid >> 3);
    int t = threadIdx.x;
    int n = lbid * 16 + (t >> 4);
    int lg = t & 15;
    int c4 = lg * 4;
    int e0 = ptr[n], e1 = ptr[n + 1];
    int cnt = e1 - e0;
    float4 acc = make_float4(0.f, 0.f, 0.f, 0.f);

    {
        int2 q[8];
#pragma unroll
        for (int i = 0; i < 8; ++i) {
            int ee = e0 + i;
            if (ee > e1 - 1) ee = e1 - 1;
            if (ee < 0) ee = 0;
            q[i] = ep[ee];
        }
#pragma unroll
        for (int i = 0; i < 8; ++i) {
            if (i < cnt) {
                float v = __int_as_float(q[i].y);
                float4 xv = *(const float4*)(yin + (size_t)q[i].x * 64 + c4);
                acc.x += v * xv.x; acc.y += v * xv.y;
                acc.z += v * xv.z; acc.w += v * xv.w;
            }
        }
    }
    if (cnt > 8) {
        int2 q[8];
#pragma unroll
        for (int i = 0; i < 8; ++i) {
            int ee = e0 + 8 + i;
            if (ee > e1 - 1) ee = e1 - 1;
            q[i] = ep[ee];
        }
#pragma unroll
        for (int i = 0; i < 8; ++i) {
            if (8 + i < cnt) {
                float v = __int_as_float(q[i].y);
                float4 xv = *(const float4*)(yin + (size_t)q[i].x * 64 + c4);
                acc.x += v * xv.x; acc.y += v * xv.y;
                acc.z += v * xv.z; acc.w += v * xv.w;
            }
        }
        for (int e = e0 + 16; e < e1; ++e) {
            int2 qq = ep[e];
            float v = __int_as_float(qq.y);
            float4 xv = *(const float4*)(yin + (size_t)qq.x * 64 + c4);
            acc.x += v * xv.x; acc.y += v * xv.y;
            acc.z += v * xv.z; acc.w += v * xv.w;
        }
    }

    size_t idx = (size_t)n * 64 + c4;
    float4 self = *(const float4*)(yin + idx);
    float4 at = *(const float4*)(a + idx);
    float4 o;
    o.x = self.x + 0.5f * acc.x + 0.5f * at.x;
    o.y = self.y + 0.5f * acc.y + 0.5f * at.y;
    o.z = self.z + 0.5f * acc.z + 0.5f * at.z;
    o.w = self.w + 0.5f * acc.w + 0.5f * at.w;
    if (LAST) {
        float4 bv = *(const float4*)(bo + c4);
        o.x = (o.x + bv.x) * 0.5f;
        o.y = (o.y + bv.y) * 0.5f;
        o.z = (o.z + bv.z) * 0.5f;
        o.w = (o.w + bv.w) * 0.5f;
    }
    *(float4*)(yout + idx) = o;
}

// ---------------- launch ----------------

extern "C" void kernel_launch(void* const* d_in, const int* in_sizes, int n_in,
                              void* d_out, int out_size, void* d_ws, size_t ws_size,
                              hipStream_t stream) {
    const float* x  = (const float*)d_in[0];
    const int* ei   = (const int*)d_in[1];
    const float* Wq = (const float*)d_in[3];
    const float* bq = (const float*)d_in[4];
    const float* Wk = (const float*)d_in[5];
    const float* bk = (const float*)d_in[6];
    const float* Wo = (const float*)d_in[7];
    const float* bo = (const float*)d_in[8];
    float* out = (float*)d_out;

    const int* row = ei;
    const int* col = ei + E_E;

    // big buffers (N*128 floats each):
    //   bufA: qs           -> later a (first N*64) + y0/yA (second N*64)
    //   bufB: ks           -> later yB ping-pong
    //   bufC: kvs partials -> later attn
    float* bufA = (float*)d_ws;
    float* bufB = bufA + (size_t)N_NODES * HD;
    float* bufC = bufB + (size_t)N_NODES * HD;
    int2*  ep   = (int2*)(bufC + (size_t)N_NODES * HD);
    float* kvs  = (float*)(ep + E_E);                 // 131072
    float* ksum = kvs + 131072;                       // 2048
    float* xsum = ksum + 2048;                        // 1024
    float* dinv = xsum + 1024;                        // N
    int* degi   = (int*)(dinv + N_NODES);             // N
    int* cursor = degi + N_NODES;                     // N
    int* ptr    = cursor + N_NODES;                   // N+1
    int* bsums  = ptr + N_NODES + 1;                  // 256

    float* a_  = bufA;                                // [N,64]
    float* yA  = bufA + (size_t)N_NODES * 64;         // [N,64]
    float* yB  = bufB;                                // [N,64]

    hipMemsetAsync(degi, 0, (size_t)N_NODES * 2 * 4, stream);
    hipMemsetAsync(ksum, 0, (size_t)(2048 + 1024) * 4, stream);

    deg_kernel<<<E_E / 256, 256, 0, stream>>>(col, degi);
    scan1<<<N_NODES / 256, 256, 0, stream>>>(degi, ptr, bsums, dinv);
    scan3<<<N_NODES / 256, 256, 0, stream>>>(ptr, bsums);
    scatter_kernel<<<E_E / 256, 256, 0, stream>>>(row, col, ptr, cursor, dinv, ep);

    proj_kernel<<<2048, 256, 0, stream>>>(x, Wq, bq, Wk, bk, bufA, bufB);

    kvs_part<<<1024, 256, 0, stream>>>(bufB, x, bufC, ksum, xsum);
    kvs_reduce<<<512, 256, 0, stream>>>(bufC, kvs);
    attn_kernel<<<1024, 256, 0, stream>>>(bufA, kvs, ksum, xsum, bufC);

    awo_kernel<<<1024, 256, 0, stream>>>(bufC, Wo, a_);
    y0_kernel<<<1024, 256, 0, stream>>>(x, Wo, yA);

    gcn64_kernel<0><<<N_NODES / 16, 256, 0, stream>>>(yA, a_, ptr, ep, yB, bo);
    gcn64_kernel<0><<<N_NODES / 16, 256, 0, stream>>>(yB, a_, ptr, ep, yA, bo);
    gcn64_kernel<0><<<N_NODES / 16, 256, 0, stream>>>(yA, a_, ptr, ep, yB, bo);
    gcn64_kernel<1><<<N_NODES / 16, 256, 0, stream>>>(yB, a_, ptr, ep, out, bo);
}

// Round 10
// 357.597 us; speedup vs baseline: 1.5837x; 1.1720x over previous
//
#include <hip/hip_runtime.h>

#define N_NODES 65536
#define B_G     16
#define NPG_    4096
#define H_H     2
#define D_D     64
#define HD      128
#define E_E     524288
#define D_OUT   64

// ---------------- degree / CSR build ----------------

__global__ void deg_kernel(const int* __restrict__ col, int* __restrict__ degi) {
    int e = blockIdx.x * 256 + threadIdx.x;
    if (e < E_E) atomicAdd(&degi[col[e]], 1);
}

__global__ void scan1(const int* __restrict__ degi, int* __restrict__ ptr,
                      int* __restrict__ bsums, float* __restrict__ dinv) {
    __shared__ int lds[256];
    int t = threadIdx.x;
    int i = blockIdx.x * 256 + t;
    int v = degi[i];
    dinv[i] = (v > 0) ? (1.0f / sqrtf((float)v)) : 0.0f;
    lds[t] = v;
    __syncthreads();
    for (int off = 1; off < 256; off <<= 1) {
        int tmp = (t >= off) ? lds[t - off] : 0;
        __syncthreads();
        lds[t] += tmp;
        __syncthreads();
    }
    ptr[i] = lds[t] - v;
    if (t == 255) bsums[blockIdx.x] = lds[255];
}

__global__ void scan3(int* __restrict__ ptr, const int* __restrict__ bsums) {
    __shared__ int red[256];
    int t = threadIdx.x;
    red[t] = (t < (int)blockIdx.x) ? bsums[t] : 0;
    __syncthreads();
    for (int off = 128; off > 0; off >>= 1) {
        if (t < off) red[t] += red[t + off];
        __syncthreads();
    }
    int i = blockIdx.x * 256 + t;
    ptr[i] += red[0];
    if (i == 0) ptr[N_NODES] = E_E;
}

__global__ void scatter_kernel(const int* __restrict__ row, const int* __restrict__ col,
                               const int* __restrict__ ptr, int* __restrict__ cursor,
                               const float* __restrict__ dinv,
                               int2* __restrict__ ep) {
    int e = blockIdx.x * 256 + threadIdx.x;
    if (e < E_E) {
        int c = col[e], r = row[e];
        int p = ptr[c] + atomicAdd(&cursor[c], 1);
        ep[p] = make_int2(r, __float_as_int(dinv[c] * dinv[r]));
    }
}

// ---------------- q/k projection + fused L2-normalize (R8, proven) ----------------
__global__ __launch_bounds__(256) void proj_kernel(
    const float* __restrict__ x,
    const float* __restrict__ Wq, const float* __restrict__ bq,
    const float* __restrict__ Wk, const float* __restrict__ bk,
    float* __restrict__ qs, float* __restrict__ ks) {
    __shared__ float4 wt4[16 * 128];
    __shared__ float4 xt4[64 * 17];
    __shared__ float bl[128];
    int t = threadIdx.x;
    int qk = blockIdx.x & 1;
    int nb = (blockIdx.x >> 1) * 64;
    const float* W = qk ? Wk : Wq;
    const float* bias = qk ? bk : bq;
    float* outp = qk ? ks : qs;

    for (int i = t; i < 2048; i += 256) {
        int k4 = i >> 7, c = i & 127;
        wt4[i] = make_float4(W[(4 * k4 + 0) * 128 + c], W[(4 * k4 + 1) * 128 + c],
                             W[(4 * k4 + 2) * 128 + c], W[(4 * k4 + 3) * 128 + c]);
    }
    const float4* xg = (const float4*)(x + (size_t)nb * 64);
    for (int i = t; i < 1024; i += 256) {
        int node = i >> 4, k4 = i & 15;
        xt4[node * 17 + k4] = xg[i];
    }
    if (t < 128) bl[t] = bias[t];
    __syncthreads();

    int cg = t & 15;
    int nd = (t >> 4) & 3;
    int w = t >> 6;
    int n_t = w * 16 + nd * 4;

    float acc[4][8];
#pragma unroll
    for (int i = 0; i < 4; ++i)
#pragma unroll
        for (int j = 0; j < 8; ++j) acc[i][j] = 0.f;

#pragma unroll 2
    for (int k4 = 0; k4 < 16; ++k4) {
        float4 xv0 = xt4[(n_t + 0) * 17 + k4];
        float4 xv1 = xt4[(n_t + 1) * 17 + k4];
        float4 xv2 = xt4[(n_t + 2) * 17 + k4];
        float4 xv3 = xt4[(n_t + 3) * 17 + k4];
#pragma unroll
        for (int j = 0; j < 8; ++j) {
            float4 wv = wt4[k4 * 128 + cg + 16 * j];
            acc[0][j] += wv.x * xv0.x + wv.y * xv0.y + wv.z * xv0.z + wv.w * xv0.w;
            acc[1][j] += wv.x * xv1.x + wv.y * xv1.y + wv.z * xv1.z + wv.w * xv1.w;
            acc[2][j] += wv.x * xv2.x + wv.y * xv2.y + wv.z * xv2.z + wv.w * xv2.w;
            acc[3][j] += wv.x * xv3.x + wv.y * xv3.y + wv.z * xv3.z + wv.w * xv3.w;
        }
    }

    float bcol[8];
#pragma unroll
    for (int j = 0; j < 8; ++j) bcol[j] = bl[cg + 16 * j];

#pragma unroll
    for (int i = 0; i < 4; ++i) {
#pragma unroll
        for (int j = 0; j < 8; ++j) acc[i][j] += bcol[j];
        float s0 = acc[i][0] * acc[i][0] + acc[i][1] * acc[i][1] +
                   acc[i][2] * acc[i][2] + acc[i][3] * acc[i][3];
        float s1 = acc[i][4] * acc[i][4] + acc[i][5] * acc[i][5] +
                   acc[i][6] * acc[i][6] + acc[i][7] * acc[i][7];
#pragma unroll
        for (int off = 8; off > 0; off >>= 1) {
            s0 += __shfl_xor(s0, off);
            s1 += __shfl_xor(s1, off);
        }
        float r0 = rsqrtf(s0), r1 = rsqrtf(s1);
        size_t base = (size_t)(nb + n_t + i) * 128 + cg;
#pragma unroll
        for (int j = 0; j < 4; ++j) outp[base + 16 * j] = acc[i][j] * r0;
#pragma unroll
        for (int j = 4; j < 8; ++j) outp[base + 16 * j] = acc[i][j] * r1;
    }
}

// ---------------- kvs stage A: per-block partials (no atomics) ----------------
__global__ __launch_bounds__(256) void kvs_part(
    const float* __restrict__ ks, const float* __restrict__ x,
    float* __restrict__ partials, float* __restrict__ ksum, float* __restrict__ xsum) {
    int bid = blockIdx.x;
    int chunk = bid & 31;
    int bh = bid >> 5;
    int b = bh >> 1, h = bh & 1;
    int t = threadIdx.x;
    int mrow = t >> 4, dcol = t & 15;
    int m0 = mrow * 4, d0 = dcol * 4;
    __shared__ float kl[32 * 64];
    __shared__ float xl[32 * 64];
    float acc[4][4] = {{0}};
    float ksacc[4] = {0, 0, 0, 0};
    float xsacc[4] = {0, 0, 0, 0};
    int node0 = b * NPG_ + chunk * 128;
    for (int s = 0; s < 4; ++s) {
        int nb = node0 + s * 32;
        for (int i = t; i < 512; i += 256) {
            int l = i >> 4, q = i & 15;
            ((float4*)kl)[i] = *(const float4*)(ks + (size_t)(nb + l) * 128 + h * 64 + q * 4);
        }
        const float4* xg = (const float4*)(x + (size_t)nb * 64);
        for (int i = t; i < 512; i += 256) ((float4*)xl)[i] = xg[i];
        __syncthreads();
        for (int l = 0; l < 32; ++l) {
            float4 kv = *(float4*)(kl + l * 64 + m0);
            float4 xv = *(float4*)(xl + l * 64 + d0);
            float kk[4] = {kv.x, kv.y, kv.z, kv.w};
            float xx[4] = {xv.x, xv.y, xv.z, xv.w};
#pragma unroll
            for (int i = 0; i < 4; ++i)
#pragma unroll
                for (int j = 0; j < 4; ++j) acc[i][j] += kk[i] * xx[j];
            if (dcol == 0) {
#pragma unroll
                for (int i = 0; i < 4; ++i) ksacc[i] += kk[i];
            }
            if (mrow == 0) {
#pragma unroll
                for (int j = 0; j < 4; ++j) xsacc[j] += xx[j];
            }
        }
        __syncthreads();
    }
    float* pout = partials + (size_t)bid * 4096;
#pragma unroll
    for (int i = 0; i < 4; ++i)
        *(float4*)(pout + (m0 + i) * 64 + d0) =
            make_float4(acc[i][0], acc[i][1], acc[i][2], acc[i][3]);
    if (dcol == 0) {
#pragma unroll
        for (int i = 0; i < 4; ++i) atomicAdd(&ksum[bh * 64 + m0 + i], ksacc[i]);
    }
    if (mrow == 0 && h == 0) {
#pragma unroll
        for (int j = 0; j < 4; ++j) atomicAdd(&xsum[b * 64 + d0 + j], xsacc[j]);
    }
}

// ---------------- kvs stage B: reduce 32 chunk-partials ----------------
__global__ __launch_bounds__(256) void kvs_reduce(
    const float* __restrict__ partials, float* __restrict__ kvs) {
    int i = blockIdx.x * 256 + threadIdx.x;
    int bh = i >> 12, elem = i & 4095;
    const float* p = partials + (size_t)bh * 32 * 4096 + elem;
    float s = 0.f;
#pragma unroll
    for (int c = 0; c < 32; ++c) s += p[c * 4096];
    kvs[i] = s;
}

// ---------------- attention output: block = 128 nodes x 1 head ----------------
__global__ __launch_bounds__(256) void attn_kernel(
    const float* __restrict__ qs, const float* __restrict__ kvs,
    const float* __restrict__ ksum, const float* __restrict__ xsum,
    float* __restrict__ attn) {
    __shared__ float ql[128 * 64];
    int bid = blockIdx.x;
    int h = bid & 1;
    int nb = (bid >> 1) * 128;
    int b = nb >> 12;
    int bh = b * 2 + h;
    int t = threadIdx.x;
    int lane = t & 63;
    for (int i = t; i < 128 * 16; i += 256) {
        int r = i >> 4, q4 = i & 15;
        ((float4*)ql)[i] = *(const float4*)(qs + (size_t)(nb + r) * 128 + h * 64 + q4 * 4);
    }
    float kvreg[64];
    const float* kvp = kvs + bh * 4096 + lane;
#pragma unroll
    for (int m = 0; m < 64; ++m) kvreg[m] = kvp[m * 64];
    float ksreg = ksum[bh * 64 + lane];
    float xs_d = xsum[b * 64 + lane];
    __syncthreads();
    int nslot = t >> 6;
    for (int nn = 0; nn < 32; ++nn) {
        int node = nn * 4 + nslot;
        const float* qrow = ql + node * 64;
        float p = qrow[lane] * ksreg;
#pragma unroll
        for (int off = 32; off > 0; off >>= 1) p += __shfl_xor(p, off);
        float den = p + 16.0f;
        float acc = 0.f;
#pragma unroll
        for (int m4 = 0; m4 < 16; ++m4) {
            float4 qv = *(const float4*)(qrow + m4 * 4);
            acc += qv.x * kvreg[4 * m4] + qv.y * kvreg[4 * m4 + 1] +
                   qv.z * kvreg[4 * m4 + 2] + qv.w * kvreg[4 * m4 + 3];
        }
        attn[(size_t)(nb + node) * 128 + h * 64 + lane] = (acc + xs_d) / den;
    }
}

// ---------------- a = attn @ Wo  (proj-style tile; XOR k-skew kills x-read conflicts) ----------------
// Block = 64 nodes. wt4[k4][col] (32KB): 16 consecutive float4s per lane-group read
// -> 2-way free. xt4[node][k4] (32KB, no pad): reads skewed kk = k4 ^ (ns&3) so the
// wave's 4 node-slots hit 4 distinct quad-banks. 8 b128 per 64 FMA -> FMA-bound.
__global__ __launch_bounds__(256) void awo_kernel(
    const float* __restrict__ attn, const float* __restrict__ Wo,
    float* __restrict__ a) {
    __shared__ float4 wt4[32 * 64];
    __shared__ float4 xt4[64 * 32];
    int t = threadIdx.x;
    int nb = blockIdx.x * 64;

    for (int i = t; i < 2048; i += 256) {
        int k4 = i >> 6, c = i & 63;
        wt4[i] = make_float4(Wo[(4 * k4 + 0) * 64 + c], Wo[(4 * k4 + 1) * 64 + c],
                             Wo[(4 * k4 + 2) * 64 + c], Wo[(4 * k4 + 3) * 64 + c]);
    }
    const float4* ag = (const float4*)(attn + (size_t)nb * 128);
    for (int i = t; i < 2048; i += 256) xt4[i] = ag[i];
    __syncthreads();

    int cg = t & 15;           // cols cg + 16j
    int ns = t >> 4;           // node slot (4 nodes)
    int s = ns & 3;            // k-skew within wave
    int n_t = ns * 4;

    float acc[4][4] = {{0.f}};
#pragma unroll 4
    for (int k4 = 0; k4 < 32; ++k4) {
        int kk = k4 ^ s;
        float4 xv0 = xt4[(n_t + 0) * 32 + kk];
        float4 xv1 = xt4[(n_t + 1) * 32 + kk];
        float4 xv2 = xt4[(n_t + 2) * 32 + kk];
        float4 xv3 = xt4[(n_t + 3) * 32 + kk];
#pragma unroll
        for (int j = 0; j < 4; ++j) {
            float4 wv = wt4[kk * 64 + cg + 16 * j];
            acc[0][j] += wv.x * xv0.x + wv.y * xv0.y + wv.z * xv0.z + wv.w * xv0.w;
            acc[1][j] += wv.x * xv1.x + wv.y * xv1.y + wv.z * xv1.z + wv.w * xv1.w;
            acc[2][j] += wv.x * xv2.x + wv.y * xv2.y + wv.z * xv2.z + wv.w * xv2.w;
            acc[3][j] += wv.x * xv3.x + wv.y * xv3.y + wv.z * xv3.z + wv.w * xv3.w;
        }
    }
#pragma unroll
    for (int i = 0; i < 4; ++i)
#pragma unroll
        for (int j = 0; j < 4; ++j)
            a[(size_t)(nb + n_t + i) * 64 + cg + 16 * j] = acc[i][j];
}

// ---------------- y0 = x @ (Wo_top + Wo_bot)  (same structure, K=64) ----------------
__global__ __launch_bounds__(256) void y0_kernel(
    const float* __restrict__ x, const float* __restrict__ Wo,
    float* __restrict__ y0) {
    __shared__ float4 wt4[16 * 64];
    __shared__ float4 xt4[64 * 16];
    int t = threadIdx.x;
    int nb = blockIdx.x * 64;

    for (int i = t; i < 1024; i += 256) {
        int k4 = i >> 6, c = i & 63;
        wt4[i] = make_float4(
            Wo[(4 * k4 + 0) * 64 + c] + Wo[(4 * k4 + 64) * 64 + c],
            Wo[(4 * k4 + 1) * 64 + c] + Wo[(4 * k4 + 65) * 64 + c],
            Wo[(4 * k4 + 2) * 64 + c] + Wo[(4 * k4 + 66) * 64 + c],
            Wo[(4 * k4 + 3) * 64 + c] + Wo[(4 * k4 + 67) * 64 + c]);
    }
    const float4* xg = (const float4*)(x + (size_t)nb * 64);
    for (int i = t; i < 1024; i += 256) xt4[i] = xg[i];
    __syncthreads();

    int cg = t & 15;
    int ns = t >> 4;
    int s = ns & 3;
    int n_t = ns * 4;

    float acc[4][4] = {{0.f}};
#pragma unroll 4
    for (int k4 = 0; k4 < 16; ++k4) {
        int kk = k4 ^ s;
        float4 xv0 = xt4[(n_t + 0) * 16 + kk];
        float4 xv1 = xt4[(n_t + 1) * 16 + kk];
        float4 xv2 = xt4[(n_t + 2) * 16 + kk];
        float4 xv3 = xt4[(n_t + 3) * 16 + kk];
#pragma unroll
        for (int j = 0; j < 4; ++j) {
            float4 wv = wt4[kk * 64 + cg + 16 * j];
            acc[0][j] += wv.x * xv0.x + wv.y * xv0.y + wv.z * xv0.z + wv.w * xv0.w;
            acc[1][j] += wv.x * xv1.x + wv.y * xv1.y + wv.z * xv1.z + wv.w * xv1.w;
            acc[2][j] += wv.x * xv2.x + wv.y * xv2.y + wv.z * xv2.z + wv.w * xv2.w;
            acc[3][j] += wv.x * xv3.x + wv.y * xv3.y + wv.z * xv3.z + wv.w * xv3.w;
        }
    }
#pragma unroll
    for (int i = 0; i < 4; ++i)
#pragma unroll
        for (int j = 0; j < 4; ++j)
            y0[(size_t)(nb + n_t + i) * 64 + cg + 16 * j] = acc[i][j];
}

// ---------------- GCN step in 64-col space ----------------
template <int LAST>
__global__ __launch_bounds__(256) void gcn64_kernel(
    const float* __restrict__ yin, const float* __restrict__ a,
    const int* __restrict__ ptr, const int2* __restrict__ ep,
    float* __restrict__ yout, const float* __restrict__ bo) {
    int bid = blockIdx.x;
    int lbid = (bid & 7) * (N_NODES / 16 / 8) + (bid >> 3);
    int t = threadIdx.x;
    int n = lbid * 16 + (t >> 4);
    int lg = t & 15;
    int c4 = lg * 4;
    int e0 = ptr[n], e1 = ptr[n + 1];
    int cnt = e1 - e0;
    float4 acc = make_float4(0.f, 0.f, 0.f, 0.f);

    {
        int2 q[8];
#pragma unroll
        for (int i = 0; i < 8; ++i) {
            int ee = e0 + i;
            if (ee > e1 - 1) ee = e1 - 1;
            if (ee < 0) ee = 0;
            q[i] = ep[ee];
        }
#pragma unroll
        for (int i = 0; i < 8; ++i) {
            if (i < cnt) {
                float v = __int_as_float(q[i].y);
                float4 xv = *(const float4*)(yin + (size_t)q[i].x * 64 + c4);
                acc.x += v * xv.x; acc.y += v * xv.y;
                acc.z += v * xv.z; acc.w += v * xv.w;
            }
        }
    }
    if (cnt > 8) {
        int2 q[8];
#pragma unroll
        for (int i = 0; i < 8; ++i) {
            int ee = e0 + 8 + i;
            if (ee > e1 - 1) ee = e1 - 1;
            q[i] = ep[ee];
        }
#pragma unroll
        for (int i = 0; i < 8; ++i) {
            if (8 + i < cnt) {
                float v = __int_as_float(q[i].y);
                float4 xv = *(const float4*)(yin + (size_t)q[i].x * 64 + c4);
                acc.x += v * xv.x; acc.y += v * xv.y;
                acc.z += v * xv.z; acc.w += v * xv.w;
            }
        }
        for (int e = e0 + 16; e < e1; ++e) {
            int2 qq = ep[e];
            float v = __int_as_float(qq.y);
            float4 xv = *(const float4*)(yin + (size_t)qq.x * 64 + c4);
            acc.x += v * xv.x; acc.y += v * xv.y;
            acc.z += v * xv.z; acc.w += v * xv.w;
        }
    }

    size_t idx = (size_t)n * 64 + c4;
    float4 self = *(const float4*)(yin + idx);
    float4 at = *(const float4*)(a + idx);
    float4 o;
    o.x = self.x + 0.5f * acc.x + 0.5f * at.x;
    o.y = self.y + 0.5f * acc.y + 0.5f * at.y;
    o.z = self.z + 0.5f * acc.z + 0.5f * at.z;
    o.w = self.w + 0.5f * acc.w + 0.5f * at.w;
    if (LAST) {
        float4 bv = *(const float4*)(bo + c4);
        o.x = (o.x + bv.x) * 0.5f;
        o.y = (o.y + bv.y) * 0.5f;
        o.z = (o.z + bv.z) * 0.5f;
        o.w = (o.w + bv.w) * 0.5f;
    }
    *(float4*)(yout + idx) = o;
}

// ---------------- launch ----------------

extern "C" void kernel_launch(void* const* d_in, const int* in_sizes, int n_in,
                              void* d_out, int out_size, void* d_ws, size_t ws_size,
                              hipStream_t stream) {
    const float* x  = (const float*)d_in[0];
    const int* ei   = (const int*)d_in[1];
    const float* Wq = (const float*)d_in[3];
    const float* bq = (const float*)d_in[4];
    const float* Wk = (const float*)d_in[5];
    const float* bk = (const float*)d_in[6];
    const float* Wo = (const float*)d_in[7];
    const float* bo = (const float*)d_in[8];
    float* out = (float*)d_out;

    const int* row = ei;
    const int* col = ei + E_E;

    float* bufA = (float*)d_ws;
    float* bufB = bufA + (size_t)N_NODES * HD;
    float* bufC = bufB + (size_t)N_NODES * HD;
    int2*  ep   = (int2*)(bufC + (size_t)N_NODES * HD);
    float* kvs  = (float*)(ep + E_E);
    float* ksum = kvs + 131072;
    float* xsum = ksum + 2048;
    float* dinv = xsum + 1024;
    int* degi   = (int*)(dinv + N_NODES);
    int* cursor = degi + N_NODES;
    int* ptr    = cursor + N_NODES;
    int* bsums  = ptr + N_NODES + 1;

    float* a_  = bufA;
    float* yA  = bufA + (size_t)N_NODES * 64;
    float* yB  = bufB;

    hipMemsetAsync(degi, 0, (size_t)N_NODES * 2 * 4, stream);
    hipMemsetAsync(ksum, 0, (size_t)(2048 + 1024) * 4, stream);

    deg_kernel<<<E_E / 256, 256, 0, stream>>>(col, degi);
    scan1<<<N_NODES / 256, 256, 0, stream>>>(degi, ptr, bsums, dinv);
    scan3<<<N_NODES / 256, 256, 0, stream>>>(ptr, bsums);
    scatter_kernel<<<E_E / 256, 256, 0, stream>>>(row, col, ptr, cursor, dinv, ep);

    proj_kernel<<<2048, 256, 0, stream>>>(x, Wq, bq, Wk, bk, bufA, bufB);

    kvs_part<<<1024, 256, 0, stream>>>(bufB, x, bufC, ksum, xsum);
    kvs_reduce<<<512, 256, 0, stream>>>(bufC, kvs);
    attn_kernel<<<1024, 256, 0, stream>>>(bufA, kvs, ksum, xsum, bufC);

    awo_kernel<<<1024, 256, 0, stream>>>(bufC, Wo, a_);
    y0_kernel<<<1024, 256, 0, stream>>>(x, Wo, yA);

    gcn64_kernel<0><<<N_NODES / 16, 256, 0, stream>>>(yA, a_, ptr, ep, yB, bo);
    gcn64_kernel<0><<<N_NODES / 16, 256, 0, stream>>>(yB, a_, ptr, ep, yA, bo);
    gcn64_kernel<0><<<N_NODES / 16, 256, 0, stream>>>(yA, a_, ptr, ep, yB, bo);
    gcn64_kernel<1><<<N_NODES / 16, 256, 0, stream>>>(yB, a_, ptr, ep, out, bo);
}